// Round 26
// baseline (185.022 us; speedup 1.0000x reference)
//
#include <hip/hip_runtime.h>
#include <math.h>

#define N_NODES 50000
#define N_EDGES 500000
#define IN_DIM 256
#define OUT_DIM 128
#define NEG_SLOPE 0.01f
#define MAX_DEG 128   // Poisson(10): P(deg>=128) ~ 1e-90 per node
#define NB_HIST 1954  // one edge per thread: 1954*256 = 500224 >= N_EDGES

typedef __attribute__((ext_vector_type(8))) short short8;
typedef __attribute__((ext_vector_type(4))) float f32x4;

// fp32 -> bf16 bits, round-to-nearest-even
__device__ __forceinline__ unsigned short f2bf(float f) {
  unsigned u = __float_as_uint(f);
  unsigned r = (u + 0x7FFFu + ((u >> 16) & 1u)) >> 16;
  return (unsigned short)r;
}
__device__ __forceinline__ float bflo(unsigned u) {
  return __uint_as_float((u & 0xFFFFu) << 16);
}
__device__ __forceinline__ float bfhi(unsigned u) {
  return __uint_as_float(u & 0xFFFF0000u);
}

// ---------------- MFMA GEMM: z = h @ W^T (z bf16), fused s1/s2 ----------------
// Stages fp32 W -> bf16 LDS with in-register cvt (no Wb buffer, no prep pass);
// also zeroes cnt/isum/done (index-disjoint; visible at kernel boundary).
// LDS 64KB XOR-swizzled; 512 threads, launch_bounds(512,4); 16 A-loads hoisted.
// C/D: lane l, reg q -> row=(l>>4)*4+q, col=l&15 [m89-verified]
__global__ __launch_bounds__(512, 4) void gemm_mfma_kernel(
    const float* __restrict__ h, const float* __restrict__ W,
    const float* __restrict__ aw, int* __restrict__ zeroed,
    unsigned short* __restrict__ zb, float* __restrict__ s1, float* __restrict__ s2) {
  __shared__ unsigned short Blds[128 * 256];  // 64 KB
  const int t    = threadIdx.x;
  const int wid  = t >> 6;
  const int lane = t & 63;
  const int row0 = blockIdx.x * 128 + wid * 16;
  const int r16  = lane & 15;
  const int kg   = lane >> 4;

  // zero cnt[50000] + isum + done (50002 ints) across the first blocks
  {
    const int gi = blockIdx.x * 512 + t;
    if (gi < N_NODES + 2) zeroed[gi] = 0;
  }

  // stage W (fp32) -> LDS (bf16, swizzled): chunk c = 8 elems of row `row`
#pragma unroll
  for (int it = 0; it < 8; ++it) {
    const int c   = it * 512 + t;        // 8-elem chunk id, 4096 total
    const int row = c >> 5, kc = c & 31;
    const float4 w0 = *(const float4*)&W[row * 256 + kc * 8];
    const float4 w1 = *(const float4*)&W[row * 256 + kc * 8 + 4];
    short8 bw;
    bw[0] = (short)f2bf(w0.x); bw[1] = (short)f2bf(w0.y);
    bw[2] = (short)f2bf(w0.z); bw[3] = (short)f2bf(w0.w);
    bw[4] = (short)f2bf(w1.x); bw[5] = (short)f2bf(w1.y);
    bw[6] = (short)f2bf(w1.z); bw[7] = (short)f2bf(w1.w);
    *(short8*)&Blds[row * 256 + ((kc ^ (row & 7)) << 3)] = bw;
  }

  const int arow = row0 + r16;
  const size_t hbase = (size_t)((arow < N_NODES) ? arow : (N_NODES - 1)) * IN_DIM;
  float4 a0[8], a1[8];
#pragma unroll
  for (int ks = 0; ks < 8; ++ks) {
    const int k0 = ks * 32 + kg * 8;
    a0[ks] = *(const float4*)&h[hbase + k0];
    a1[ks] = *(const float4*)&h[hbase + k0 + 4];
  }

  f32x4 acc[8];
#pragma unroll
  for (int ct = 0; ct < 8; ++ct) acc[ct] = (f32x4)(0.f);

  __syncthreads();

#pragma unroll
  for (int ks = 0; ks < 8; ++ks) {
    const int k0 = ks * 32 + kg * 8;
    short8 af;
    af[0] = (short)f2bf(a0[ks].x); af[1] = (short)f2bf(a0[ks].y);
    af[2] = (short)f2bf(a0[ks].z); af[3] = (short)f2bf(a0[ks].w);
    af[4] = (short)f2bf(a1[ks].x); af[5] = (short)f2bf(a1[ks].y);
    af[6] = (short)f2bf(a1[ks].z); af[7] = (short)f2bf(a1[ks].w);
#pragma unroll
    for (int ct = 0; ct < 8; ++ct) {
      const int brow = ct * 16 + r16;
      const short8 bf =
          *(const short8*)&Blds[brow * 256 + (k0 ^ ((r16 & 7) << 3))];
      acc[ct] = __builtin_amdgcn_mfma_f32_16x16x32_bf16(af, bf, acc[ct], 0, 0, 0);
    }
  }

#pragma unroll
  for (int q = 0; q < 4; ++q) {
    const int zr = row0 + kg * 4 + q;
    if (zr < N_NODES) {
#pragma unroll
      for (int ct = 0; ct < 8; ++ct)
        zb[(size_t)zr * OUT_DIM + ct * 16 + r16] = f2bf(acc[ct][q]);
    }
  }

  float p1[4] = {0.f, 0.f, 0.f, 0.f}, p2[4] = {0.f, 0.f, 0.f, 0.f};
#pragma unroll
  for (int ct = 0; ct < 8; ++ct) {
    const float w1 = aw[ct * 16 + r16];
    const float w2 = aw[128 + ct * 16 + r16];
#pragma unroll
    for (int q = 0; q < 4; ++q) {
      p1[q] += acc[ct][q] * w1;
      p2[q] += acc[ct][q] * w2;
    }
  }
#pragma unroll
  for (int off = 8; off; off >>= 1) {
#pragma unroll
    for (int q = 0; q < 4; ++q) {
      p1[q] += __shfl_xor(p1[q], off);
      p2[q] += __shfl_xor(p2[q], off);
    }
  }
  if (r16 == 0) {
#pragma unroll
    for (int q = 0; q < 4; ++q) {
      const int zr = row0 + kg * 4 + q;
      if (zr < N_NODES) { s1[zr] = p1[q]; s2[zr] = p2[q]; }
    }
  }
}

// ---------------- fused: dist mean + degree count + packed slot scatter + LUT ----------------
// ONE EDGE PER THREAD (R25 fix: 256-block grid was 8% occupancy, 45us —
// latency-bound on the atomic+scatter chain). 7813 waves hide the latency.
// LAST BLOCK (done-counter pattern) computes the 100-entry pmf LUT in-kernel.
__global__ __launch_bounds__(256) void mean_hist_kernel(
    const int* __restrict__ dist, const int* __restrict__ dst,
    const int* __restrict__ src,
    int* __restrict__ isum, int* __restrict__ done, int* __restrict__ cnt,
    unsigned* __restrict__ slots, float* __restrict__ lut) {
  int tid = blockIdx.x * blockDim.x + threadIdx.x;
  int stride = gridDim.x * blockDim.x;
  int acc = 0;
  for (int i = tid; i < N_EDGES; i += stride) {
    const int dd = dist[i];
    const int d  = dst[i];
    acc += dd;
    const int r = atomicAdd(&cnt[d], 1);
    if (r < MAX_DEG)
      slots[(size_t)d * MAX_DEG + r] = (unsigned)src[i] | ((unsigned)dd << 16);
  }
#pragma unroll
  for (int off = 32; off; off >>= 1) acc += __shfl_down(acc, off);
  if ((threadIdx.x & 63) == 0) atomicAdd(isum, acc);

  // last-block LUT computation
  __shared__ int islast;
  __syncthreads();
  if (threadIdx.x == 0) {
    __threadfence();
    islast = (atomicAdd(done, 1) == (int)gridDim.x - 1) ? 1 : 0;
  }
  __syncthreads();
  if (islast && threadIdx.x < 100) {
    const int sv = atomicAdd(isum, 0);       // coherent read of final sum
    const float mu = (float)sv * (1.0f / N_EDGES);
    const float k = (float)(threadIdx.x >> 1);
    lut[threadIdx.x] = expf(k * logf(mu) - mu - lgammaf(k + 1.0f));
  }
}

// ---------------- node kernel: one wave per node; e computed inline ----------------
// Prologue (all lanes): load packed slot (coalesced), gather s1[src], compute
// xe = exp(lut[dist]*leaky(s1+s2n)) [shift-invariant: |e|<=~0.3], park (xe,src)
// in per-wave LDS strip. Walk: quarter q handles edge jj+q via ONE broadcast
// ds_read_b64 + ONE uint4 VMEM gather per 4 edges. Fold via shfl_down(16/32);
// lanes 0-15 write the 512B output row. Grid 12500*4 = 50000 exactly.
__global__ __launch_bounds__(256) void node_kernel(
    const int* __restrict__ cnt, const unsigned* __restrict__ slots,
    const float* __restrict__ s1, const float* __restrict__ s2,
    const float* __restrict__ lut,
    const uint4* __restrict__ zb4, float* __restrict__ out) {
  __shared__ uint2 pl[4][MAX_DEG];   // (xe bits, src) per wave: 4KB
  const int wid = threadIdx.x >> 6, lane = threadIdx.x & 63;
  const int n = blockIdx.x * 4 + wid;
  const size_t beg = (size_t)n * MAX_DEG;
  const int deg = min(cnt[n], MAX_DEG);

  const int q     = lane >> 4;   // 0..3: edge slot within group of 4
  const int laneQ = lane & 15;   // 16B chunk within the 256B row

  float acc[8] = {0.f, 0.f, 0.f, 0.f, 0.f, 0.f, 0.f, 0.f};
  if (deg > 0) {
    const float s2n = s2[n];
    float ss = 0.f;
    for (int j = lane; j < deg; j += 64) {
      const unsigned pk = slots[beg + j];
      const unsigned sidx = pk & 0xFFFFu;
      const float a = s1[sidx] + s2n;
      const float lr = (a >= 0.f) ? a : NEG_SLOPE * a;
      const float xe = expf(lut[pk >> 16] * lr);
      pl[wid][j] = make_uint2(__float_as_uint(xe), sidx);
      ss += xe;
    }
#pragma unroll
    for (int off = 32; off; off >>= 1) ss += __shfl_xor(ss, off);
    const float inv = 1.0f / ss;

#pragma unroll 2
    for (int jj = 0; jj < deg; jj += 4) {
      int j2 = jj + q;
      const float w = (j2 < deg) ? 1.0f : 0.0f;
      j2 = (j2 < deg) ? j2 : jj;
      const uint2 pr = pl[wid][j2];            // broadcast ds_read_b64
      const float al = __uint_as_float(pr.x) * inv * w;
      const uint4 v = zb4[(size_t)pr.y * 16 + laneQ];
      acc[0] += al * bflo(v.x); acc[1] += al * bfhi(v.x);
      acc[2] += al * bflo(v.y); acc[3] += al * bfhi(v.y);
      acc[4] += al * bflo(v.z); acc[5] += al * bfhi(v.z);
      acc[6] += al * bflo(v.w); acc[7] += al * bfhi(v.w);
    }
  }

#pragma unroll
  for (int k = 0; k < 8; ++k) {
    acc[k] += __shfl_down(acc[k], 16);
    acc[k] += __shfl_down(acc[k], 32);
  }
  if (lane < 16) {
    float* orow = &out[(size_t)n * OUT_DIM + laneQ * 8];
    *(float4*)&orow[0] = make_float4(acc[0], acc[1], acc[2], acc[3]);
    *(float4*)&orow[4] = make_float4(acc[4], acc[5], acc[6], acc[7]);
  }
}

extern "C" void kernel_launch(void* const* d_in, const int* in_sizes, int n_in,
                              void* d_out, int out_size, void* d_ws, size_t ws_size,
                              hipStream_t stream) {
  const float* h    = (const float*)d_in[0];
  const float* fc_w = (const float*)d_in[1];
  const float* attn = (const float*)d_in[2];
  const int*   src  = (const int*)d_in[3];
  const int*   dst  = (const int*)d_in[4];
  const int*   dist = (const int*)d_in[5];
  float* out = (float*)d_out;
  float* ws  = (float*)d_ws;

  // workspace layout (4-byte units), total ~9.75M words = 39 MB
  unsigned short* zb    = (unsigned short*)ws;        // 6,400,000 bf16 = 3,200,000 words
  float*          s1    = ws + 3200000;               //    50,000
  float*          s2    = ws + 3250000;               //    50,000
  int*            cnt   = (int*)(ws + 3300000);       //    50,000 (degree counts)
  int*            isum  = (int*)(ws + 3350000);       //         1
  int*            done  = (int*)(ws + 3350001);       //         1
  float*          lut   = ws + 3350004;               //       100
  unsigned*       slots = (unsigned*)(ws + 3350104);  // 6,400,000 (packed src|dist<<16)

  // 3-kernel pipeline: gemm (also zeroes cnt/isum/done, cvt-stages W) ->
  // mean_hist (one edge/thread; also computes LUT in last block) -> node
  gemm_mfma_kernel<<<(N_NODES + 127) / 128, 512, 0, stream>>>(
      h, fc_w, attn, cnt, zb, s1, s2);
  mean_hist_kernel<<<NB_HIST, 256, 0, stream>>>(
      dist, dst, src, isum, done, cnt, slots, lut);
  node_kernel<<<N_NODES / 4, 256, 0, stream>>>(
      cnt, slots, s1, s2, lut, (const uint4*)zb, out);
}

// Round 27
// 76.722 us; speedup vs baseline: 2.4116x; 2.4116x over previous
//
#include <hip/hip_runtime.h>
#include <math.h>

#define N_NODES 50000
#define N_EDGES 500000
#define IN_DIM 256
#define OUT_DIM 128
#define NEG_SLOPE 0.01f
#define MAX_DEG 128   // Poisson(10): P(deg>=128) ~ 1e-90 per node
#define NB_GEMM 391   // ceil(50000/128) gemm blocks
#define NB_HB   128   // hist blocks x 512 thr = 65536 threads (R24-proven atomic pressure)

typedef __attribute__((ext_vector_type(8))) short short8;
typedef __attribute__((ext_vector_type(4))) float f32x4;

// fp32 -> bf16 bits, round-to-nearest-even
__device__ __forceinline__ unsigned short f2bf(float f) {
  unsigned u = __float_as_uint(f);
  unsigned r = (u + 0x7FFFu + ((u >> 16) & 1u)) >> 16;
  return (unsigned short)r;
}
__device__ __forceinline__ float bflo(unsigned u) {
  return __uint_as_float((u & 0xFFFFu) << 16);
}
__device__ __forceinline__ float bfhi(unsigned u) {
  return __uint_as_float(u & 0xFFFF0000u);
}

// ---------------- zero cnt+isum+done (50002 ints) ----------------
__global__ __launch_bounds__(512) void zero_kernel(int* __restrict__ p) {
  const int i = blockIdx.x * 512 + threadIdx.x;
  if (i < N_NODES + 2) p[i] = 0;
}

// ---------------- FUSED: gemm (blocks 0..390) || mean_hist (blocks 391..518) ----------
// No data dependency between paths: gemm reads h/W/aw -> zb,s1,s2; hist reads
// dist/dst/src -> cnt,slots,isum,lut. Hist's ~45us atomic-throughput wall
// (R24/R26: 65k in-flight = 4.6 RMW/cyc; 500k in-flight = 0.7 — wall, not
// latency) now overlaps gemm instead of serializing after it.
__global__ __launch_bounds__(512, 4) void gemm_hist_kernel(
    const float* __restrict__ h, const float* __restrict__ W,
    const float* __restrict__ aw,
    const int* __restrict__ dist, const int* __restrict__ dst,
    const int* __restrict__ src,
    int* __restrict__ isum, int* __restrict__ done, int* __restrict__ cnt,
    unsigned* __restrict__ slots, float* __restrict__ lut,
    unsigned short* __restrict__ zb, float* __restrict__ s1, float* __restrict__ s2) {
  __shared__ unsigned short Blds[128 * 256];  // 64 KB (gemm path)
  __shared__ int islast;                      // (hist path)

  if (blockIdx.x >= NB_GEMM) {
    // ---------------- hist path: 128 blocks x 512 threads ----------------
    const int hb = blockIdx.x - NB_GEMM;
    const int tid = hb * 512 + threadIdx.x;
    const int stride = NB_HB * 512;
    int acc = 0;
    for (int i = tid; i < N_EDGES; i += stride) {
      const int dd = dist[i];
      const int d  = dst[i];
      acc += dd;
      const int r = atomicAdd(&cnt[d], 1);
      if (r < MAX_DEG)
        slots[(size_t)d * MAX_DEG + r] = (unsigned)src[i] | ((unsigned)dd << 16);
    }
#pragma unroll
    for (int off = 32; off; off >>= 1) acc += __shfl_down(acc, off);
    if ((threadIdx.x & 63) == 0) atomicAdd(isum, acc);

    __syncthreads();
    if (threadIdx.x == 0) {
      __threadfence();
      islast = (atomicAdd(done, 1) == NB_HB - 1) ? 1 : 0;
    }
    __syncthreads();
    if (islast && threadIdx.x < 100) {
      const int sv = atomicAdd(isum, 0);     // coherent read of final sum
      const float mu = (float)sv * (1.0f / N_EDGES);
      const float k = (float)(threadIdx.x >> 1);
      lut[threadIdx.x] = expf(k * logf(mu) - mu - lgammaf(k + 1.0f));
    }
    return;
  }

  // ---------------- gemm path (identical to R24, minus zeroing) ----------------
  const int t    = threadIdx.x;
  const int wid  = t >> 6;
  const int lane = t & 63;
  const int row0 = blockIdx.x * 128 + wid * 16;
  const int r16  = lane & 15;
  const int kg   = lane >> 4;

  // stage W (fp32) -> LDS (bf16, swizzled)
#pragma unroll
  for (int it = 0; it < 8; ++it) {
    const int c   = it * 512 + t;
    const int row = c >> 5, kc = c & 31;
    const float4 w0 = *(const float4*)&W[row * 256 + kc * 8];
    const float4 w1 = *(const float4*)&W[row * 256 + kc * 8 + 4];
    short8 bw;
    bw[0] = (short)f2bf(w0.x); bw[1] = (short)f2bf(w0.y);
    bw[2] = (short)f2bf(w0.z); bw[3] = (short)f2bf(w0.w);
    bw[4] = (short)f2bf(w1.x); bw[5] = (short)f2bf(w1.y);
    bw[6] = (short)f2bf(w1.z); bw[7] = (short)f2bf(w1.w);
    *(short8*)&Blds[row * 256 + ((kc ^ (row & 7)) << 3)] = bw;
  }

  const int arow = row0 + r16;
  const size_t hbase = (size_t)((arow < N_NODES) ? arow : (N_NODES - 1)) * IN_DIM;
  float4 a0[8], a1[8];
#pragma unroll
  for (int ks = 0; ks < 8; ++ks) {
    const int k0 = ks * 32 + kg * 8;
    a0[ks] = *(const float4*)&h[hbase + k0];
    a1[ks] = *(const float4*)&h[hbase + k0 + 4];
  }

  f32x4 acc[8];
#pragma unroll
  for (int ct = 0; ct < 8; ++ct) acc[ct] = (f32x4)(0.f);

  __syncthreads();

#pragma unroll
  for (int ks = 0; ks < 8; ++ks) {
    const int k0 = ks * 32 + kg * 8;
    short8 af;
    af[0] = (short)f2bf(a0[ks].x); af[1] = (short)f2bf(a0[ks].y);
    af[2] = (short)f2bf(a0[ks].z); af[3] = (short)f2bf(a0[ks].w);
    af[4] = (short)f2bf(a1[ks].x); af[5] = (short)f2bf(a1[ks].y);
    af[6] = (short)f2bf(a1[ks].z); af[7] = (short)f2bf(a1[ks].w);
#pragma unroll
    for (int ct = 0; ct < 8; ++ct) {
      const int brow = ct * 16 + r16;
      const short8 bf =
          *(const short8*)&Blds[brow * 256 + (k0 ^ ((r16 & 7) << 3))];
      acc[ct] = __builtin_amdgcn_mfma_f32_16x16x32_bf16(af, bf, acc[ct], 0, 0, 0);
    }
  }

#pragma unroll
  for (int q = 0; q < 4; ++q) {
    const int zr = row0 + kg * 4 + q;
    if (zr < N_NODES) {
#pragma unroll
      for (int ct = 0; ct < 8; ++ct)
        zb[(size_t)zr * OUT_DIM + ct * 16 + r16] = f2bf(acc[ct][q]);
    }
  }

  float p1[4] = {0.f, 0.f, 0.f, 0.f}, p2[4] = {0.f, 0.f, 0.f, 0.f};
#pragma unroll
  for (int ct = 0; ct < 8; ++ct) {
    const float w1 = aw[ct * 16 + r16];
    const float w2 = aw[128 + ct * 16 + r16];
#pragma unroll
    for (int q = 0; q < 4; ++q) {
      p1[q] += acc[ct][q] * w1;
      p2[q] += acc[ct][q] * w2;
    }
  }
#pragma unroll
  for (int off = 8; off; off >>= 1) {
#pragma unroll
    for (int q = 0; q < 4; ++q) {
      p1[q] += __shfl_xor(p1[q], off);
      p2[q] += __shfl_xor(p2[q], off);
    }
  }
  if (r16 == 0) {
#pragma unroll
    for (int q = 0; q < 4; ++q) {
      const int zr = row0 + kg * 4 + q;
      if (zr < N_NODES) { s1[zr] = p1[q]; s2[zr] = p2[q]; }
    }
  }
}

// ---------------- node kernel: one wave per node; e computed inline ----------------
// Prologue (all lanes): load packed slot (coalesced), gather s1[src], compute
// xe = exp(lut[dist]*leaky(s1+s2n)) [shift-invariant: |e|<=~0.3], park (xe,src)
// in per-wave LDS strip. Walk: quarter q handles edge jj+q via ONE broadcast
// ds_read_b64 + ONE uint4 VMEM gather per 4 edges. Fold via shfl_down(16/32);
// lanes 0-15 write the 512B output row. Grid 12500*4 = 50000 exactly.
__global__ __launch_bounds__(256) void node_kernel(
    const int* __restrict__ cnt, const unsigned* __restrict__ slots,
    const float* __restrict__ s1, const float* __restrict__ s2,
    const float* __restrict__ lut,
    const uint4* __restrict__ zb4, float* __restrict__ out) {
  __shared__ uint2 pl[4][MAX_DEG];   // (xe bits, src) per wave: 4KB
  const int wid = threadIdx.x >> 6, lane = threadIdx.x & 63;
  const int n = blockIdx.x * 4 + wid;
  const size_t beg = (size_t)n * MAX_DEG;
  const int deg = min(cnt[n], MAX_DEG);

  const int q     = lane >> 4;   // 0..3: edge slot within group of 4
  const int laneQ = lane & 15;   // 16B chunk within the 256B row

  float acc[8] = {0.f, 0.f, 0.f, 0.f, 0.f, 0.f, 0.f, 0.f};
  if (deg > 0) {
    const float s2n = s2[n];
    float ss = 0.f;
    for (int j = lane; j < deg; j += 64) {
      const unsigned pk = slots[beg + j];
      const unsigned sidx = pk & 0xFFFFu;
      const float a = s1[sidx] + s2n;
      const float lr = (a >= 0.f) ? a : NEG_SLOPE * a;
      const float xe = expf(lut[pk >> 16] * lr);
      pl[wid][j] = make_uint2(__float_as_uint(xe), sidx);
      ss += xe;
    }
#pragma unroll
    for (int off = 32; off; off >>= 1) ss += __shfl_xor(ss, off);
    const float inv = 1.0f / ss;

#pragma unroll 2
    for (int jj = 0; jj < deg; jj += 4) {
      int j2 = jj + q;
      const float w = (j2 < deg) ? 1.0f : 0.0f;
      j2 = (j2 < deg) ? j2 : jj;
      const uint2 pr = pl[wid][j2];            // broadcast ds_read_b64
      const float al = __uint_as_float(pr.x) * inv * w;
      const uint4 v = zb4[(size_t)pr.y * 16 + laneQ];
      acc[0] += al * bflo(v.x); acc[1] += al * bfhi(v.x);
      acc[2] += al * bflo(v.y); acc[3] += al * bfhi(v.y);
      acc[4] += al * bflo(v.z); acc[5] += al * bfhi(v.z);
      acc[6] += al * bflo(v.w); acc[7] += al * bfhi(v.w);
    }
  }

#pragma unroll
  for (int k = 0; k < 8; ++k) {
    acc[k] += __shfl_down(acc[k], 16);
    acc[k] += __shfl_down(acc[k], 32);
  }
  if (lane < 16) {
    float* orow = &out[(size_t)n * OUT_DIM + laneQ * 8];
    *(float4*)&orow[0] = make_float4(acc[0], acc[1], acc[2], acc[3]);
    *(float4*)&orow[4] = make_float4(acc[4], acc[5], acc[6], acc[7]);
  }
}

extern "C" void kernel_launch(void* const* d_in, const int* in_sizes, int n_in,
                              void* d_out, int out_size, void* d_ws, size_t ws_size,
                              hipStream_t stream) {
  const float* h    = (const float*)d_in[0];
  const float* fc_w = (const float*)d_in[1];
  const float* attn = (const float*)d_in[2];
  const int*   src  = (const int*)d_in[3];
  const int*   dst  = (const int*)d_in[4];
  const int*   dist = (const int*)d_in[5];
  float* out = (float*)d_out;
  float* ws  = (float*)d_ws;

  // workspace layout (4-byte units), total ~9.75M words = 39 MB
  unsigned short* zb    = (unsigned short*)ws;        // 6,400,000 bf16 = 3,200,000 words
  float*          s1    = ws + 3200000;               //    50,000
  float*          s2    = ws + 3250000;               //    50,000
  int*            cnt   = (int*)(ws + 3300000);       //    50,000 (degree counts)
  int*            isum  = (int*)(ws + 3350000);       //         1
  int*            done  = (int*)(ws + 3350001);       //         1
  float*          lut   = ws + 3350004;               //       100
  unsigned*       slots = (unsigned*)(ws + 3350104);  // 6,400,000 (packed src|dist<<16)

  // 3-kernel pipeline: zero -> fused gemm||hist -> node
  zero_kernel<<<98, 512, 0, stream>>>(cnt);   // cnt+isum+done contiguous
  gemm_hist_kernel<<<NB_GEMM + NB_HB, 512, 0, stream>>>(
      h, fc_w, attn, dist, dst, src, isum, done, cnt, slots, lut, zb, s1, s2);
  node_kernel<<<N_NODES / 4, 256, 0, stream>>>(
      cnt, slots, s1, s2, lut, (const uint4*)zb, out);
}

// Round 29
// 76.310 us; speedup vs baseline: 2.4246x; 1.0054x over previous
//
#include <hip/hip_runtime.h>
#include <math.h>

#define N_NODES 50000
#define N_EDGES 500000
#define IN_DIM 256
#define OUT_DIM 128
#define NEG_SLOPE 0.01f
#define MAX_DEG 128   // Poisson(10): P(deg>=128) ~ 1e-90 per node
#define NB_GEMM 391   // ceil(50000/128) gemm blocks
#define NB_HB   128   // hist blocks x 512 thr = 65536 threads
#define HSTRIDE (NB_HB * 512)

typedef __attribute__((ext_vector_type(8))) short short8;
typedef __attribute__((ext_vector_type(4))) float f32x4;

// fp32 -> bf16 bits, round-to-nearest-even
__device__ __forceinline__ unsigned short f2bf(float f) {
  unsigned u = __float_as_uint(f);
  unsigned r = (u + 0x7FFFu + ((u >> 16) & 1u)) >> 16;
  return (unsigned short)r;
}
__device__ __forceinline__ float bflo(unsigned u) {
  return __uint_as_float((u & 0xFFFFu) << 16);
}
__device__ __forceinline__ float bfhi(unsigned u) {
  return __uint_as_float(u & 0xFFFF0000u);
}

// ---------------- zero cnt+isum+done (50002 ints) ----------------
__global__ __launch_bounds__(512) void zero_kernel(int* __restrict__ p) {
  const int i = blockIdx.x * 512 + threadIdx.x;
  if (i < N_NODES + 2) p[i] = 0;
}

// ---------------- FUSED: gemm (blocks 0..390) || mean_hist (blocks 391..518) ----------
// Hist path MLP restructure (R27 fix): phase 1 issues ALL 8 atomics
// back-to-back (returns pending, no dependent work between them — R23's fast
// ~17 RMW/cyc regime); phase 2 drains the 8 scatter stores. Full unroll keeps
// rk/pk/dp in registers (static indices, rule #20).
__global__ __launch_bounds__(512, 4) void gemm_hist_kernel(
    const float* __restrict__ h, const float* __restrict__ W,
    const float* __restrict__ aw,
    const int* __restrict__ dist, const int* __restrict__ dst,
    const int* __restrict__ src,
    int* __restrict__ isum, int* __restrict__ done, int* __restrict__ cnt,
    unsigned* __restrict__ slots, float* __restrict__ lut,
    unsigned short* __restrict__ zb, float* __restrict__ s1, float* __restrict__ s2) {
  __shared__ unsigned short Blds[128 * 256];  // 64 KB (gemm path)
  __shared__ int islast;                      // (hist path)

  if (blockIdx.x >= NB_GEMM) {
    // ---------------- hist path: 128 blocks x 512 threads ----------------
    const int hb = blockIdx.x - NB_GEMM;
    const int tid = hb * 512 + threadIdx.x;
    int acc = 0;
    int rk[8]; unsigned pk[8]; int dp[8];
    // phase 1: loads + atomics, no dependent stores in between
#pragma unroll
    for (int b = 0; b < 8; ++b) {
      const int i = tid + b * HSTRIDE;
      if (i < N_EDGES) {
        const int dd = dist[i];
        const int d  = dst[i];
        acc += dd;
        dp[b] = d;
        pk[b] = (unsigned)src[i] | ((unsigned)dd << 16);
        rk[b] = atomicAdd(&cnt[d], 1);
      } else {
        rk[b] = MAX_DEG;  // sentinel: skip in phase 2
      }
    }
    // phase 2: drain scatter stores
#pragma unroll
    for (int b = 0; b < 8; ++b) {
      if (rk[b] < MAX_DEG)
        slots[(size_t)dp[b] * MAX_DEG + rk[b]] = pk[b];
    }
#pragma unroll
    for (int off = 32; off; off >>= 1) acc += __shfl_down(acc, off);
    if ((threadIdx.x & 63) == 0) atomicAdd(isum, acc);

    __syncthreads();
    if (threadIdx.x == 0) {
      __threadfence();
      islast = (atomicAdd(done, 1) == NB_HB - 1) ? 1 : 0;
    }
    __syncthreads();
    if (islast && threadIdx.x < 100) {
      const int sv = atomicAdd(isum, 0);     // coherent read of final sum
      const float mu = (float)sv * (1.0f / N_EDGES);
      const float k = (float)(threadIdx.x >> 1);
      lut[threadIdx.x] = expf(k * logf(mu) - mu - lgammaf(k + 1.0f));
    }
    return;
  }

  // ---------------- gemm path ----------------
  const int t    = threadIdx.x;
  const int wid  = t >> 6;
  const int lane = t & 63;
  const int row0 = blockIdx.x * 128 + wid * 16;
  const int r16  = lane & 15;
  const int kg   = lane >> 4;

  // stage W (fp32) -> LDS (bf16, swizzled)
#pragma unroll
  for (int it = 0; it < 8; ++it) {
    const int c   = it * 512 + t;
    const int row = c >> 5, kc = c & 31;
    const float4 w0 = *(const float4*)&W[row * 256 + kc * 8];
    const float4 w1 = *(const float4*)&W[row * 256 + kc * 8 + 4];
    short8 bw;
    bw[0] = (short)f2bf(w0.x); bw[1] = (short)f2bf(w0.y);
    bw[2] = (short)f2bf(w0.z); bw[3] = (short)f2bf(w0.w);
    bw[4] = (short)f2bf(w1.x); bw[5] = (short)f2bf(w1.y);
    bw[6] = (short)f2bf(w1.z); bw[7] = (short)f2bf(w1.w);
    *(short8*)&Blds[row * 256 + ((kc ^ (row & 7)) << 3)] = bw;
  }

  const int arow = row0 + r16;
  const size_t hbase = (size_t)((arow < N_NODES) ? arow : (N_NODES - 1)) * IN_DIM;
  float4 a0[8], a1[8];
#pragma unroll
  for (int ks = 0; ks < 8; ++ks) {
    const int k0 = ks * 32 + kg * 8;
    a0[ks] = *(const float4*)&h[hbase + k0];
    a1[ks] = *(const float4*)&h[hbase + k0 + 4];
  }

  f32x4 acc[8];
#pragma unroll
  for (int ct = 0; ct < 8; ++ct) acc[ct] = (f32x4)(0.f);

  __syncthreads();

#pragma unroll
  for (int ks = 0; ks < 8; ++ks) {
    const int k0 = ks * 32 + kg * 8;
    short8 af;
    af[0] = (short)f2bf(a0[ks].x); af[1] = (short)f2bf(a0[ks].y);
    af[2] = (short)f2bf(a0[ks].z); af[3] = (short)f2bf(a0[ks].w);
    af[4] = (short)f2bf(a1[ks].x); af[5] = (short)f2bf(a1[ks].y);
    af[6] = (short)f2bf(a1[ks].z); af[7] = (short)f2bf(a1[ks].w);
#pragma unroll
    for (int ct = 0; ct < 8; ++ct) {
      const int brow = ct * 16 + r16;
      const short8 bf =
          *(const short8*)&Blds[brow * 256 + (k0 ^ ((r16 & 7) << 3))];
      acc[ct] = __builtin_amdgcn_mfma_f32_16x16x32_bf16(af, bf, acc[ct], 0, 0, 0);
    }
  }

#pragma unroll
  for (int q = 0; q < 4; ++q) {
    const int zr = row0 + kg * 4 + q;
    if (zr < N_NODES) {
#pragma unroll
      for (int ct = 0; ct < 8; ++ct)
        zb[(size_t)zr * OUT_DIM + ct * 16 + r16] = f2bf(acc[ct][q]);
    }
  }

  float p1[4] = {0.f, 0.f, 0.f, 0.f}, p2[4] = {0.f, 0.f, 0.f, 0.f};
#pragma unroll
  for (int ct = 0; ct < 8; ++ct) {
    const float w1 = aw[ct * 16 + r16];
    const float w2 = aw[128 + ct * 16 + r16];
#pragma unroll
    for (int q = 0; q < 4; ++q) {
      p1[q] += acc[ct][q] * w1;
      p2[q] += acc[ct][q] * w2;
    }
  }
#pragma unroll
  for (int off = 8; off; off >>= 1) {
#pragma unroll
    for (int q = 0; q < 4; ++q) {
      p1[q] += __shfl_xor(p1[q], off);
      p2[q] += __shfl_xor(p2[q], off);
    }
  }
  if (r16 == 0) {
#pragma unroll
    for (int q = 0; q < 4; ++q) {
      const int zr = row0 + kg * 4 + q;
      if (zr < N_NODES) { s1[zr] = p1[q]; s2[zr] = p2[q]; }
    }
  }
}

// ---------------- node kernel: one wave per node; e computed inline ----------------
__global__ __launch_bounds__(256) void node_kernel(
    const int* __restrict__ cnt, const unsigned* __restrict__ slots,
    const float* __restrict__ s1, const float* __restrict__ s2,
    const float* __restrict__ lut,
    const uint4* __restrict__ zb4, float* __restrict__ out) {
  __shared__ uint2 pl[4][MAX_DEG];   // (xe bits, src) per wave: 4KB
  const int wid = threadIdx.x >> 6, lane = threadIdx.x & 63;
  const int n = blockIdx.x * 4 + wid;
  const size_t beg = (size_t)n * MAX_DEG;
  const int deg = min(cnt[n], MAX_DEG);

  const int q     = lane >> 4;   // 0..3: edge slot within group of 4
  const int laneQ = lane & 15;   // 16B chunk within the 256B row

  float acc[8] = {0.f, 0.f, 0.f, 0.f, 0.f, 0.f, 0.f, 0.f};
  if (deg > 0) {
    const float s2n = s2[n];
    float ss = 0.f;
    for (int j = lane; j < deg; j += 64) {
      const unsigned pk = slots[beg + j];
      const unsigned sidx = pk & 0xFFFFu;
      const float a = s1[sidx] + s2n;
      const float lr = (a >= 0.f) ? a : NEG_SLOPE * a;
      const float xe = expf(lut[pk >> 16] * lr);
      pl[wid][j] = make_uint2(__float_as_uint(xe), sidx);
      ss += xe;
    }
#pragma unroll
    for (int off = 32; off; off >>= 1) ss += __shfl_xor(ss, off);
    const float inv = 1.0f / ss;

#pragma unroll 2
    for (int jj = 0; jj < deg; jj += 4) {
      int j2 = jj + q;
      const float w = (j2 < deg) ? 1.0f : 0.0f;
      j2 = (j2 < deg) ? j2 : jj;
      const uint2 pr = pl[wid][j2];            // broadcast ds_read_b64
      const float al = __uint_as_float(pr.x) * inv * w;
      const uint4 v = zb4[(size_t)pr.y * 16 + laneQ];
      acc[0] += al * bflo(v.x); acc[1] += al * bfhi(v.x);
      acc[2] += al * bflo(v.y); acc[3] += al * bfhi(v.y);
      acc[4] += al * bflo(v.z); acc[5] += al * bfhi(v.z);
      acc[6] += al * bflo(v.w); acc[7] += al * bfhi(v.w);
    }
  }

#pragma unroll
  for (int k = 0; k < 8; ++k) {
    acc[k] += __shfl_down(acc[k], 16);
    acc[k] += __shfl_down(acc[k], 32);
  }
  if (lane < 16) {
    float* orow = &out[(size_t)n * OUT_DIM + laneQ * 8];
    *(float4*)&orow[0] = make_float4(acc[0], acc[1], acc[2], acc[3]);
    *(float4*)&orow[4] = make_float4(acc[4], acc[5], acc[6], acc[7]);
  }
}

extern "C" void kernel_launch(void* const* d_in, const int* in_sizes, int n_in,
                              void* d_out, int out_size, void* d_ws, size_t ws_size,
                              hipStream_t stream) {
  const float* h    = (const float*)d_in[0];
  const float* fc_w = (const float*)d_in[1];
  const float* attn = (const float*)d_in[2];
  const int*   src  = (const int*)d_in[3];
  const int*   dst  = (const int*)d_in[4];
  const int*   dist = (const int*)d_in[5];
  float* out = (float*)d_out;
  float* ws  = (float*)d_ws;

  // workspace layout (4-byte units), total ~9.75M words = 39 MB
  unsigned short* zb    = (unsigned short*)ws;        // 6,400,000 bf16 = 3,200,000 words
  float*          s1    = ws + 3200000;               //    50,000
  float*          s2    = ws + 3250000;               //    50,000
  int*            cnt   = (int*)(ws + 3300000);       //    50,000 (degree counts)
  int*            isum  = (int*)(ws + 3350000);       //         1
  int*            done  = (int*)(ws + 3350001);       //         1
  float*          lut   = ws + 3350004;               //       100
  unsigned*       slots = (unsigned*)(ws + 3350104);  // 6,400,000 (packed src|dist<<16)

  // 3-kernel pipeline: zero -> fused gemm||hist -> node
  zero_kernel<<<98, 512, 0, stream>>>(cnt);   // cnt+isum+done contiguous
  gemm_hist_kernel<<<NB_GEMM + NB_HB, 512, 0, stream>>>(
      h, fc_w, attn, dist, dst, src, isum, done, cnt, slots, lut, zb, s1, s2);
  node_kernel<<<N_NODES / 4, 256, 0, stream>>>(
      cnt, slots, s1, s2, lut, (const uint4*)zb, out);
}